// Round 6
// baseline (796.497 us; speedup 1.0000x reference)
//
#include <hip/hip_runtime.h>
#include <hip/hip_bf16.h>

// ---------------- problem constants ----------------
constexpr int Bc = 32, Sc = 4096, Ic = 64, Hc = 512, Oc = 64;
constexpr int Lc = 64;             // chunk length (timesteps per block)
constexpr int NCc = Sc / Lc;       // 64 chunks
constexpr int HSUB = 128;          // h-subtile width
constexpr int NSUB = Hc / HSUB;    // 4 subtiles
constexpr int WPB = 4;             // waves per block (16 t-rows each)

typedef __attribute__((ext_vector_type(8))) short short8;
typedef __attribute__((ext_vector_type(4))) float float4v;

__device__ __forceinline__ short f2bf(float f) {
    unsigned u = __builtin_bit_cast(unsigned, f);
    u += 0x7FFFu + ((u >> 16) & 1u);   // RNE
    return (short)(u >> 16);
}

// XOR-swizzle for the LDS h tile (row-major [64][256B]). (row&15)<<4 spreads
// all 16 rows of a wave's fragment reads across distinct 16B slots -> the
// ds_read_b128 column reads are conflict-free; same function on write & read.
__device__ __forceinline__ int swz(int row, int byteInRow) {
    return row * 256 + (byteInRow ^ ((row & 15) << 4));
}

// ---------------- K0: weights -> MFMA-fragment-ordered bf16 ----------------
// bfrag slot s = ((hsu*8+hj)*2+ks)*64 + l : lane l's short8 for that B-frag.
// cfrag slot s = ((hsu*4+ks)*4+oj)*64 + l. Coalesced 1KB wave loads at use.
__global__ void prep_weights(const float* __restrict__ bw, const float* __restrict__ cw,
                             short* __restrict__ bfrag, short* __restrict__ cfrag) {
    int s = blockIdx.x * 256 + threadIdx.x;   // 8192 total
    int l = s & 63, g = (l >> 4), lr = l & 15;
    if (s < 4096) {
        int ks = (s >> 6) & 1, hj = (s >> 7) & 7, hsu = (s >> 10) & 3;
        short8 v;
#pragma unroll
        for (int j = 0; j < 8; j++)
            v[j] = f2bf(bw[(ks * 32 + g * 8 + j) * Hc + hsu * HSUB + hj * 16 + lr]);
        *(short8*)(bfrag + (size_t)s * 8) = v;
    } else {
        int idx = s - 4096;
        int oj = (idx >> 6) & 3, ks = (idx >> 8) & 3, hsu = (idx >> 10) & 3;
        short8 v;
#pragma unroll
        for (int j = 0; j < 8; j++)
            v[j] = f2bf(cw[(hsu * HSUB + ks * 32 + g * 8 + j) * Oc + oj * 16 + lr]);
        *(short8*)(cfrag + (size_t)idx * 8) = v;
    }
}

// ---------------- fused single-pass kernel with decoupled lookback ----------
// Ticket-ordered virtual block ids guarantee lookback progress regardless of
// HW dispatch order: a ticket exists only for blocks already executing, and
// every block publishes its aggregate BEFORE it spins on predecessors.
__global__ __launch_bounds__(256, 3) void fused(
    const float* __restrict__ x, const short* __restrict__ bfrag,
    const short* __restrict__ cfrag, const float* __restrict__ Adiag,
    float* __restrict__ aggVal, float* __restrict__ inclVal,
    int* __restrict__ flags, int* __restrict__ ticket,
    float* __restrict__ out) {
    __shared__ char hbuf[64 * 256];      // [t][h-sub] bf16, swizzled, 16 KB (own-wave rows only)
    __shared__ float aggw[2][WPB][HSUB]; // wave 16-step totals -> per-wave carries, dbuf, 4 KB
    __shared__ int vshare;

    const int tid = threadIdx.x;
    const int l = tid & 63, wid = tid >> 6;
    const int lr = l & 15, g = l >> 4;

    if (tid == 0)
        vshare = __hip_atomic_fetch_add(ticket, 1, __ATOMIC_RELAXED, __HIP_MEMORY_SCOPE_AGENT);
    __syncthreads();
    const int v = vshare;
    const int b = v & 31, chunk = v >> 5;   // chunk increases with ticket per batch

    // ---- X fragments: direct global f32 -> bf16 (wave's 16 t-rows) ----
    short8 xf[2];
    {
        const float* xr = x + ((size_t)b * Sc + chunk * Lc + wid * 16 + lr) * Ic + g * 8;
#pragma unroll
        for (int ks = 0; ks < 2; ks++) {
            float4v v0 = *(const float4v*)(xr + ks * 32);
            float4v v1 = *(const float4v*)(xr + ks * 32 + 4);
            short8 f;
            f[0] = f2bf(v0[0]); f[1] = f2bf(v0[1]); f[2] = f2bf(v0[2]); f[3] = f2bf(v0[3]);
            f[4] = f2bf(v1[0]); f[5] = f2bf(v1[1]); f[6] = f2bf(v1[2]); f[7] = f2bf(v1[3]);
            xf[ks] = f;
        }
    }

    float4v yacc[4];
#pragma unroll
    for (int j = 0; j < 4; j++) yacc[j] = (float4v)0.f;

#pragma unroll 1
    for (int hsu = 0; hsu < NSUB; hsu++) {
        const int buf = hsu & 1;
        float4v acc[8];    // lane-local xb -> in-wave inclusive scan values
        float areg[8];     // per-hj decay for the correction phase

        // ---- xb = X @ b (coalesced fragment loads, L2-resident) ----
#pragma unroll
        for (int hj = 0; hj < 8; hj++) {
            const short8* bfp = (const short8*)bfrag + ((hsu * 8 + hj) * 2) * 64 + l;
            short8 b0 = bfp[0];
            short8 b1 = bfp[64];
            float4v t = (float4v)0.f;
            t = __builtin_amdgcn_mfma_f32_16x16x32_bf16(xf[0], b0, t, 0, 0, 0);
            t = __builtin_amdgcn_mfma_f32_16x16x32_bf16(xf[1], b1, t, 0, 0, 0);
            acc[hj] = t;
        }

        // ---- in-wave zero-init scan over 16 t-steps ----
        // lane holds t = wid*16 + 4g + r ; column = hj*16 + lr
#pragma unroll
        for (int hj = 0; hj < 8; hj++) {
            float a = Adiag[hsu * HSUB + hj * 16 + lr];
            areg[hj] = a;
            float a2 = a * a, a3 = a2 * a, a4 = a2 * a2, a8 = a4 * a4;
            // lane-local inclusive 4-step scan
            acc[hj][1] = fmaf(acc[hj][0], a, acc[hj][1]);
            acc[hj][2] = fmaf(acc[hj][1], a, acc[hj][2]);
            acc[hj][3] = fmaf(acc[hj][2], a, acc[hj][3]);
            // Hillis-Steele across the 4 lane-groups (stride 16)
            float s = acc[hj][3];
            float u = __shfl_up(s, 16u, 64); s = (g >= 1) ? fmaf(u, a4, s) : s;
            u = __shfl_up(s, 32u, 64);       s = (g >= 2) ? fmaf(u, a8, s) : s;
            float E = __shfl_up(s, 16u, 64); E = (g >= 1) ? E : 0.f;   // in-wave exclusive
            // fold in-wave prefix now; carry correction deferred to after lookback
#pragma unroll
            for (int r = 0; r < 4; r++) {
                float apr = (r == 0) ? a : (r == 1) ? a2 : (r == 2) ? a3 : a4;
                acc[hj][r] = fmaf(apr, E, acc[hj][r]);
            }
            float S16 = __shfl(s, lr + 48, 64);   // wave 16-step total
            if (l < 16) aggw[buf][wid][hj * 16 + l] = S16;
            if (hj & 1) __builtin_amdgcn_sched_barrier(0);
        }
        __syncthreads();   // wave totals visible

        // ---- publish aggregate, lookback, per-wave carries (h-col per thread) ----
        const size_t gidx = (size_t)(b * NCc + chunk) * Hc + hsu * HSUB;
        const int fi = (b * NCc + chunk) * NSUB + hsu;
        float aC, a16C, a64C, s0C, s1C, s2C, s3C, TC;
        if (tid < HSUB) {
            aC = Adiag[hsu * HSUB + tid];
            float t2 = aC * aC, t4 = t2 * t2, t8 = t4 * t4;
            a16C = t8 * t8;
            float t32 = a16C * a16C;
            a64C = t32 * t32;
            s0C = aggw[buf][0][tid]; s1C = aggw[buf][1][tid];
            s2C = aggw[buf][2][tid]; s3C = aggw[buf][3][tid];
            TC = fmaf(fmaf(fmaf(s0C, a16C, s1C), a16C, s2C), a16C, s3C);  // chunk total
            aggVal[gidx + tid] = TC;
        }
        __syncthreads();   // aggVal complete before flag release
        if (tid == 0)
            __hip_atomic_store(&flags[fi], 1, __ATOMIC_RELEASE, __HIP_MEMORY_SCOPE_AGENT);

        if (tid < HSUB) {
            float C = 0.f;
            if (chunk > 0) {
                float m = 1.f;
                for (int j = chunk - 1; j >= 0; --j) {
                    const int fj = (b * NCc + j) * NSUB + hsu;
                    int f;
                    while ((f = __hip_atomic_load(&flags[fj], __ATOMIC_ACQUIRE,
                                                  __HIP_MEMORY_SCOPE_AGENT)) == 0)
                        __builtin_amdgcn_s_sleep(2);
                    const size_t gj = (size_t)(b * NCc + j) * Hc + hsu * HSUB + tid;
                    if (f == 2) { C = fmaf(m, inclVal[gj], C); break; }
                    C = fmaf(m, aggVal[gj], C);
                    m *= a64C;
                }
            }
            inclVal[gidx + tid] = fmaf(a64C, C, TC);
            // per-wave carries (state entering wave w), overwrite aggw in place
            float P = C;
            aggw[buf][0][tid] = P; P = fmaf(a16C, P, s0C);
            aggw[buf][1][tid] = P; P = fmaf(a16C, P, s1C);
            aggw[buf][2][tid] = P; P = fmaf(a16C, P, s2C);
            aggw[buf][3][tid] = P;
        }
        __syncthreads();   // inclVal + carries ready
        if (tid == 0)
            __hip_atomic_store(&flags[fi], 2, __ATOMIC_RELEASE, __HIP_MEMORY_SCOPE_AGENT);

        // ---- carry correction, h -> LDS (own-wave rows, no barrier) ----
#pragma unroll
        for (int hj = 0; hj < 8; hj++) {
            float cw_ = aggw[buf][wid][hj * 16 + lr];
            float a = areg[hj];
            float a2 = a * a, a3 = a2 * a, a4 = a2 * a2, a8 = a4 * a4;
            float a4g = ((g & 1) ? a4 : 1.f) * ((g & 2) ? a8 : 1.f);
            float cc = a4g * cw_;
#pragma unroll
            for (int r = 0; r < 4; r++) {
                float apr = (r == 0) ? a : (r == 1) ? a2 : (r == 2) ? a3 : a4;
                float hv = fmaf(apr, cc, acc[hj][r]);
                *(short*)(hbuf + swz(wid * 16 + g * 4 + r, (hj * 16 + lr) * 2)) = f2bf(hv);
            }
        }

        // ---- y += h @ c (A-frags from own-wave hbuf rows) ----
#pragma unroll
        for (int ks = 0; ks < 4; ks++) {
            short8 af = *(const short8*)(hbuf + swz(wid * 16 + lr, ks * 64 + g * 16));
#pragma unroll
            for (int oj = 0; oj < 4; oj++) {
                short8 cf = *((const short8*)cfrag + ((hsu * 4 + ks) * 4 + oj) * 64 + l);
                yacc[oj] = __builtin_amdgcn_mfma_f32_16x16x32_bf16(af, cf, yacc[oj], 0, 0, 0);
            }
        }
    }

    // ---- write y tile (wave's 16 rows x 64 o) ----
    float* og = out + ((size_t)b * Sc + chunk * Lc) * Oc;
#pragma unroll
    for (int oj = 0; oj < 4; oj++)
#pragma unroll
        for (int r = 0; r < 4; r++) {
            int t = wid * 16 + g * 4 + r;
            og[t * Oc + oj * 16 + lr] = yacc[oj][r];
        }
}

// ---------------- host launch ----------------
extern "C" void kernel_launch(void* const* d_in, const int* in_sizes, int n_in,
                              void* d_out, int out_size, void* d_ws, size_t ws_size,
                              hipStream_t stream) {
    (void)in_sizes; (void)n_in; (void)out_size; (void)ws_size;
    const float* x     = (const float*)d_in[0];   // [B,S,I] f32
    const float* bw    = (const float*)d_in[1];   // [I,H]   f32
    const float* Adiag = (const float*)d_in[2];   // [H]     f32
    const float* cw    = (const float*)d_in[3];   // [H,O]   f32
    float* out = (float*)d_out;                   // [B,S*O] f32

    // workspace layout (~8.4 MB)
    float* aggVal  = (float*)d_ws;                         // [B][NC][H] f32, 4 MB
    float* inclVal = aggVal + (size_t)Bc * NCc * Hc;       // [B][NC][H] f32, 4 MB
    short* bfrag   = (short*)(inclVal + (size_t)Bc * NCc * Hc);  // 64 KB
    short* cfrag   = bfrag + 4096 * 8;                           // 64 KB
    int*   flags   = (int*)(cfrag + 4096 * 8);             // [B][NC][NSUB], 32 KB
    int*   ticket  = flags + Bc * NCc * NSUB;              // 1 int

    // flags + ticket must be zero every launch (ws is poisoned 0xAA)
    hipMemsetAsync(flags, 0, (Bc * NCc * NSUB + 1) * sizeof(int), stream);
    prep_weights<<<32, 256, 0, stream>>>(bw, cw, bfrag, cfrag);
    fused<<<Bc * NCc, 256, 0, stream>>>(x, bfrag, cfrag, Adiag,
                                        aggVal, inclVal, flags, ticket, out);
}

// Round 8
// 223.413 us; speedup vs baseline: 3.5651x; 3.5651x over previous
//
#include <hip/hip_runtime.h>
#include <hip/hip_bf16.h>

// ---------------- problem constants ----------------
constexpr int Bc = 32, Sc = 4096, Ic = 64, Hc = 512, Oc = 64;
constexpr int Lc = 64;             // chunk length (timesteps per block)
constexpr int NCc = Sc / Lc;       // 64 chunks
constexpr int HSUB = 128;          // h-subtile width
constexpr int NSUB = Hc / HSUB;    // 4 subtiles
constexpr int WPB = 4;             // waves per block (16 t-rows each)

typedef __attribute__((ext_vector_type(8))) short short8;
typedef __attribute__((ext_vector_type(4))) float float4v;

__device__ __forceinline__ short f2bf(float f) {
    unsigned u = __builtin_bit_cast(unsigned, f);
    u += 0x7FFFu + ((u >> 16) & 1u);   // RNE
    return (short)(u >> 16);
}

// XOR-swizzle for the LDS h tile (row-major [64][256B]). (row&15)<<4 spreads
// a wave's 16 fragment-read rows across distinct 16B slots (R6: measured
// SQ_LDS_BANK_CONFLICT = 0). Same function on write & read.
__device__ __forceinline__ int swz(int row, int byteInRow) {
    return row * 256 + (byteInRow ^ ((row & 15) << 4));
}

// ---------------- K0: weights -> MFMA-fragment-ordered bf16 ----------------
// bfrag slot s = ((hsu*8+hj)*2+ks)*64 + l : lane l's short8 for that B-frag.
// cfrag slot s = ((hsu*4+ks)*4+oj)*64 + l. Coalesced 1KB wave loads at use.
__global__ void prep_weights(const float* __restrict__ bw, const float* __restrict__ cw,
                             short* __restrict__ bfrag, short* __restrict__ cfrag) {
    int s = blockIdx.x * 256 + threadIdx.x;   // 8192 total
    int l = s & 63, g = (l >> 4), lr = l & 15;
    if (s < 4096) {
        int ks = (s >> 6) & 1, hj = (s >> 7) & 7, hsu = (s >> 10) & 3;
        short8 v;
#pragma unroll
        for (int j = 0; j < 8; j++)
            v[j] = f2bf(bw[(ks * 32 + g * 8 + j) * Hc + hsu * HSUB + hj * 16 + lr]);
        *(short8*)(bfrag + (size_t)s * 8) = v;
    } else {
        int idx = s - 4096;
        int oj = (idx >> 6) & 3, ks = (idx >> 8) & 3, hsu = (idx >> 10) & 3;
        short8 v;
#pragma unroll
        for (int j = 0; j < 8; j++)
            v[j] = f2bf(cw[(hsu * HSUB + ks * 32 + g * 8 + j) * Oc + oj * 16 + lr]);
        *(short8*)(cfrag + (size_t)idx * 8) = v;
    }
}

// ---------------- shared helper: wave's 16-row X fragments ------------------
__device__ __forceinline__ void load_xfrag(const float* __restrict__ x, int b, int t0,
                                           int wid, int lr, int g, short8 xf[2]) {
    const float* xr = x + ((size_t)b * Sc + t0 + wid * 16 + lr) * Ic + g * 8;
#pragma unroll
    for (int ks = 0; ks < 2; ks++) {
        float4v v0 = *(const float4v*)(xr + ks * 32);
        float4v v1 = *(const float4v*)(xr + ks * 32 + 4);
        short8 f;
        f[0] = f2bf(v0[0]); f[1] = f2bf(v0[1]); f[2] = f2bf(v0[2]); f[3] = f2bf(v0[3]);
        f[4] = f2bf(v1[0]); f[5] = f2bf(v1[1]); f[6] = f2bf(v1[2]); f[7] = f2bf(v1[3]);
        xf[ks] = f;
    }
}

// ---------------- K1: per-chunk zero-init totals -> wlast -------------------
__global__ __launch_bounds__(256, 4) void pass1(
    const float* __restrict__ x, const short* __restrict__ bfrag,
    const float* __restrict__ Adiag, float* __restrict__ wlast) {
    __shared__ float aggw[2][WPB][HSUB];   // wave 16-step totals, dbuf, 4 KB

    const int tid = threadIdx.x;
    const int chunk = blockIdx.x, b = blockIdx.y;
    const int l = tid & 63, wid = tid >> 6;
    const int lr = l & 15, g = l >> 4;

    short8 xf[2];
    load_xfrag(x, b, chunk * Lc, wid, lr, g, xf);

#pragma unroll 1
    for (int hsu = 0; hsu < NSUB; hsu++) {
        const int buf = hsu & 1;
#pragma unroll
        for (int hj = 0; hj < 8; hj++) {
            const short8* bfp = (const short8*)bfrag + ((hsu * 8 + hj) * 2) * 64 + l;
            short8 b0 = bfp[0];
            short8 b1 = bfp[64];
            float4v t = (float4v)0.f;
            t = __builtin_amdgcn_mfma_f32_16x16x32_bf16(xf[0], b0, t, 0, 0, 0);
            t = __builtin_amdgcn_mfma_f32_16x16x32_bf16(xf[1], b1, t, 0, 0, 0);
            // lane holds t-rows 4g..4g+3 of the wave's 16, column hj*16+lr
            float a = Adiag[hsu * HSUB + hj * 16 + lr];
            float a2 = a * a, a4 = a2 * a2, a8 = a4 * a4;
            float s = fmaf(fmaf(fmaf(t[0], a, t[1]), a, t[2]), a, t[3]);   // 4-step total
            float u = __shfl_up(s, 16u, 64); s = (g >= 1) ? fmaf(u, a4, s) : s;
            u = __shfl_up(s, 32u, 64);       s = (g >= 2) ? fmaf(u, a8, s) : s;
            float S16 = __shfl(s, lr + 48, 64);   // wave 16-step total
            if (l < 16) aggw[buf][wid][hj * 16 + l] = S16;
        }
        __syncthreads();
        if (tid < HSUB) {
            float a = Adiag[hsu * HSUB + tid];
            float t2 = a * a, t4 = t2 * t2, t8 = t4 * t4;
            float a16 = t8 * t8;
            float T = fmaf(fmaf(fmaf(aggw[buf][0][tid], a16, aggw[buf][1][tid]), a16,
                                aggw[buf][2][tid]), a16, aggw[buf][3][tid]);
            wlast[(size_t)(b * NCc + chunk) * Hc + hsu * HSUB + tid] = T;
        }
    }
}

// ---------------- K2: in-place wlast -> exclusive chunk carries -------------
__global__ void carry2(const float* __restrict__ Adiag, float* __restrict__ wl) {
    int gid = blockIdx.x * 256 + threadIdx.x;   // 16384 = B*H
    int b = gid >> 9, h = gid & (Hc - 1);
    float a = Adiag[h];
    float a64 = a;
#pragma unroll
    for (int i = 0; i < 6; i++) a64 *= a64;     // a^64
    float run = 0.f;
#pragma unroll 4
    for (int k = 0; k < NCc; k++) {
        size_t idx = ((size_t)b * NCc + k) * Hc + h;
        float tmp = wl[idx];
        wl[idx] = run;
        run = fmaf(a64, run, tmp);
    }
}

// ---------------- K3: full scan + fused y = h @ c ---------------------------
__global__ __launch_bounds__(256, 4) void pass2(
    const float* __restrict__ x, const short* __restrict__ bfrag,
    const short* __restrict__ cfrag, const float* __restrict__ Adiag,
    const float* __restrict__ carryC, float* __restrict__ out) {
    __shared__ char hbuf[64 * 256];        // [t][h-sub] bf16, swizzled, 16 KB
    __shared__ float aggw[2][WPB][HSUB];   // wave totals -> per-wave carries, dbuf

    const int tid = threadIdx.x;
    const int chunk = blockIdx.x, b = blockIdx.y;
    const int l = tid & 63, wid = tid >> 6;
    const int lr = l & 15, g = l >> 4;

    short8 xf[2];
    load_xfrag(x, b, chunk * Lc, wid, lr, g, xf);

    float4v yacc[4];
#pragma unroll
    for (int j = 0; j < 4; j++) yacc[j] = (float4v)0.f;

#pragma unroll 1
    for (int hsu = 0; hsu < NSUB; hsu++) {
        const int buf = hsu & 1;
        float4v acc[8];   // lane-local xb -> in-wave inclusive scan values
        float areg[8];

        // ---- xb MFMA + in-wave scan (8 independent chains, free scheduling) ----
#pragma unroll
        for (int hj = 0; hj < 8; hj++) {
            const short8* bfp = (const short8*)bfrag + ((hsu * 8 + hj) * 2) * 64 + l;
            short8 b0 = bfp[0];
            short8 b1 = bfp[64];
            float4v t = (float4v)0.f;
            t = __builtin_amdgcn_mfma_f32_16x16x32_bf16(xf[0], b0, t, 0, 0, 0);
            t = __builtin_amdgcn_mfma_f32_16x16x32_bf16(xf[1], b1, t, 0, 0, 0);
            float a = Adiag[hsu * HSUB + hj * 16 + lr];
            areg[hj] = a;
            float a2 = a * a, a3 = a2 * a, a4 = a2 * a2, a8 = a4 * a4;
            // lane-local inclusive 4-step scan
            t[1] = fmaf(t[0], a, t[1]); t[2] = fmaf(t[1], a, t[2]); t[3] = fmaf(t[2], a, t[3]);
            // Hillis-Steele across the 4 lane-groups
            float s = t[3];
            float u = __shfl_up(s, 16u, 64); s = (g >= 1) ? fmaf(u, a4, s) : s;
            u = __shfl_up(s, 32u, 64);       s = (g >= 2) ? fmaf(u, a8, s) : s;
            float E = __shfl_up(s, 16u, 64); E = (g >= 1) ? E : 0.f;   // in-wave exclusive
#pragma unroll
            for (int r = 0; r < 4; r++) {
                float apr = (r == 0) ? a : (r == 1) ? a2 : (r == 2) ? a3 : a4;
                t[r] = fmaf(apr, E, t[r]);
            }
            acc[hj] = t;
            float S16 = __shfl(s, lr + 48, 64);
            if (l < 16) aggw[buf][wid][hj * 16 + l] = S16;
        }
        __syncthreads();   // wave totals visible

        // ---- chunk carry -> per-wave carries (in-place overwrite) ----
        if (tid < HSUB) {
            float a = Adiag[hsu * HSUB + tid];
            float t2 = a * a, t4 = t2 * t2, t8 = t4 * t4;
            float a16 = t8 * t8;
            float C = carryC[(size_t)(b * NCc + chunk) * Hc + hsu * HSUB + tid];
            float s0 = aggw[buf][0][tid], s1 = aggw[buf][1][tid], s2 = aggw[buf][2][tid];
            float P = C;
            aggw[buf][0][tid] = P; P = fmaf(a16, P, s0);
            aggw[buf][1][tid] = P; P = fmaf(a16, P, s1);
            aggw[buf][2][tid] = P; P = fmaf(a16, P, s2);
            aggw[buf][3][tid] = P;
        }
        __syncthreads();   // carries ready

        // ---- carry correction, h -> LDS (own-wave rows, no barrier) ----
#pragma unroll
        for (int hj = 0; hj < 8; hj++) {
            float P = aggw[buf][wid][hj * 16 + lr];
            float a = areg[hj];
            float a2 = a * a, a3 = a2 * a, a4 = a2 * a2, a8 = a4 * a4;
            float a4g = ((g & 1) ? a4 : 1.f) * ((g & 2) ? a8 : 1.f);
            float cc = a4g * P;
#pragma unroll
            for (int r = 0; r < 4; r++) {
                float apr = (r == 0) ? a : (r == 1) ? a2 : (r == 2) ? a3 : a4;
                float hv = fmaf(apr, cc, acc[hj][r]);
                *(short*)(hbuf + swz(wid * 16 + g * 4 + r, (hj * 16 + lr) * 2)) = f2bf(hv);
            }
        }

        // ---- y += h @ c (A-frags from own-wave hbuf rows) ----
#pragma unroll
        for (int ks = 0; ks < 4; ks++) {
            short8 af = *(const short8*)(hbuf + swz(wid * 16 + lr, ks * 64 + g * 16));
#pragma unroll
            for (int oj = 0; oj < 4; oj++) {
                short8 cf = *((const short8*)cfrag + ((hsu * 4 + ks) * 4 + oj) * 64 + l);
                yacc[oj] = __builtin_amdgcn_mfma_f32_16x16x32_bf16(af, cf, yacc[oj], 0, 0, 0);
            }
        }
    }

    // ---- write y tile (wave's 16 rows x 64 o) ----
    float* og = out + ((size_t)b * Sc + chunk * Lc) * Oc;
#pragma unroll
    for (int oj = 0; oj < 4; oj++)
#pragma unroll
        for (int r = 0; r < 4; r++) {
            int t = wid * 16 + g * 4 + r;
            og[t * Oc + oj * 16 + lr] = yacc[oj][r];
        }
}

// ---------------- host launch ----------------
extern "C" void kernel_launch(void* const* d_in, const int* in_sizes, int n_in,
                              void* d_out, int out_size, void* d_ws, size_t ws_size,
                              hipStream_t stream) {
    (void)in_sizes; (void)n_in; (void)out_size; (void)ws_size;
    const float* x     = (const float*)d_in[0];   // [B,S,I] f32
    const float* bw    = (const float*)d_in[1];   // [I,H]   f32
    const float* Adiag = (const float*)d_in[2];   // [H]     f32
    const float* cw    = (const float*)d_in[3];   // [H,O]   f32
    float* out = (float*)d_out;                   // [B,S*O] f32

    // workspace: ~4.2 MB
    float* wlast = (float*)d_ws;                              // [B][NC][H] f32, 4 MB
    short* bfrag = (short*)(wlast + (size_t)Bc * NCc * Hc);   // 64 KB
    short* cfrag = bfrag + 4096 * 8;                          // 64 KB

    prep_weights<<<32, 256, 0, stream>>>(bw, cw, bfrag, cfrag);
    pass1<<<dim3(NCc, Bc), 256, 0, stream>>>(x, bfrag, Adiag, wlast);
    carry2<<<64, 256, 0, stream>>>(Adiag, wlast);
    pass2<<<dim3(NCc, Bc), 256, 0, stream>>>(x, bfrag, cfrag, Adiag, wlast, out);
}

// Round 11
// 172.244 us; speedup vs baseline: 4.6242x; 1.2971x over previous
//
#include <hip/hip_runtime.h>
#include <hip/hip_bf16.h>

// ---------------- problem constants ----------------
constexpr int Bc = 32, Sc = 4096, Ic = 64, Hc = 512, Oc = 64;
constexpr int Lc = 64;             // chunk length (timesteps per block)
constexpr int NCc = Sc / Lc;       // 64 chunks
constexpr int HSUB = 128;          // h-subtile width
constexpr int NSUB = Hc / HSUB;    // 4 subtiles
constexpr int WPB = 4;             // waves per block (16 t-rows each)

typedef __attribute__((ext_vector_type(8))) short short8;
typedef __attribute__((ext_vector_type(4))) float float4v;

__device__ __forceinline__ short f2bf(float f) {
    unsigned u = __builtin_bit_cast(unsigned, f);
    u += 0x7FFFu + ((u >> 16) & 1u);   // RNE
    return (short)(u >> 16);
}

// XOR-swizzle for the LDS h tile (row-major [64][256B]). (row&15)<<4 spreads
// a wave's 16 fragment-read rows across distinct 16B slots (R6/R8: measured
// SQ_LDS_BANK_CONFLICT = 0). Same function on write & read.
__device__ __forceinline__ int swz(int row, int byteInRow) {
    return row * 256 + (byteInRow ^ ((row & 15) << 4));
}

// ---------------- K0: weights -> MFMA-fragment-ordered bf16 ----------------
__global__ void prep_weights(const float* __restrict__ bw, const float* __restrict__ cw,
                             short* __restrict__ bfrag, short* __restrict__ cfrag) {
    int s = blockIdx.x * 256 + threadIdx.x;   // 8192 total
    int l = s & 63, g = (l >> 4), lr = l & 15;
    if (s < 4096) {
        int ks = (s >> 6) & 1, hj = (s >> 7) & 7, hsu = (s >> 10) & 3;
        short8 v;
#pragma unroll
        for (int j = 0; j < 8; j++)
            v[j] = f2bf(bw[(ks * 32 + g * 8 + j) * Hc + hsu * HSUB + hj * 16 + lr]);
        *(short8*)(bfrag + (size_t)s * 8) = v;
    } else {
        int idx = s - 4096;
        int oj = (idx >> 6) & 3, ks = (idx >> 8) & 3, hsu = (idx >> 10) & 3;
        short8 v;
#pragma unroll
        for (int j = 0; j < 8; j++)
            v[j] = f2bf(cw[(hsu * HSUB + ks * 32 + g * 8 + j) * Oc + oj * 16 + lr]);
        *(short8*)(cfrag + (size_t)idx * 8) = v;
    }
}

// ---------------- shared helper: wave's 16-row X fragments ------------------
__device__ __forceinline__ void load_xfrag(const float* __restrict__ x, int b, int t0,
                                           int wid, int lr, int g, short8 xf[2]) {
    const float* xr = x + ((size_t)b * Sc + t0 + wid * 16 + lr) * Ic + g * 8;
#pragma unroll
    for (int ks = 0; ks < 2; ks++) {
        float4v v0 = *(const float4v*)(xr + ks * 32);
        float4v v1 = *(const float4v*)(xr + ks * 32 + 4);
        short8 f;
        f[0] = f2bf(v0[0]); f[1] = f2bf(v0[1]); f[2] = f2bf(v0[2]); f[3] = f2bf(v0[3]);
        f[4] = f2bf(v1[0]); f[5] = f2bf(v1[1]); f[6] = f2bf(v1[2]); f[7] = f2bf(v1[3]);
        xf[ks] = f;
    }
}

// ---------------- K1: per-chunk zero-init totals -> wlast -------------------
// Small live set (no persistent accumulators) -> 4 waves/EU is safe here.
__global__ __launch_bounds__(256, 4) void pass1(
    const float* __restrict__ x, const short* __restrict__ bfrag,
    const float* __restrict__ Adiag, float* __restrict__ wlast) {
    __shared__ float aggw[2][WPB][HSUB];   // wave 16-step totals, dbuf, 4 KB

    const int tid = threadIdx.x;
    const int chunk = blockIdx.x, b = blockIdx.y;
    const int l = tid & 63, wid = tid >> 6;
    const int lr = l & 15, g = l >> 4;

    short8 xf[2];
    load_xfrag(x, b, chunk * Lc, wid, lr, g, xf);

#pragma unroll 1
    for (int hsu = 0; hsu < NSUB; hsu++) {
        const int buf = hsu & 1;
#pragma unroll
        for (int hj = 0; hj < 8; hj++) {
            const short8* bfp = (const short8*)bfrag + ((hsu * 8 + hj) * 2) * 64 + l;
            short8 b0 = bfp[0];
            short8 b1 = bfp[64];
            float4v t = (float4v)0.f;
            t = __builtin_amdgcn_mfma_f32_16x16x32_bf16(xf[0], b0, t, 0, 0, 0);
            t = __builtin_amdgcn_mfma_f32_16x16x32_bf16(xf[1], b1, t, 0, 0, 0);
            // lane holds t-rows 4g..4g+3 of the wave's 16, column hj*16+lr
            float a = Adiag[hsu * HSUB + hj * 16 + lr];
            float a2 = a * a, a4 = a2 * a2, a8 = a4 * a4;
            float s = fmaf(fmaf(fmaf(t[0], a, t[1]), a, t[2]), a, t[3]);   // 4-step total
            float u = __shfl_up(s, 16u, 64); s = (g >= 1) ? fmaf(u, a4, s) : s;
            u = __shfl_up(s, 32u, 64);       s = (g >= 2) ? fmaf(u, a8, s) : s;
            float S16 = __shfl(s, lr + 48, 64);   // wave 16-step total
            if (l < 16) aggw[buf][wid][hj * 16 + l] = S16;
        }
        __syncthreads();
        if (tid < HSUB) {
            float a = Adiag[hsu * HSUB + tid];
            float t2 = a * a, t4 = t2 * t2, t8 = t4 * t4;
            float a16 = t8 * t8;
            float T = fmaf(fmaf(fmaf(aggw[buf][0][tid], a16, aggw[buf][1][tid]), a16,
                                aggw[buf][2][tid]), a16, aggw[buf][3][tid]);
            wlast[(size_t)(b * NCc + chunk) * Hc + hsu * HSUB + tid] = T;
        }
    }
}

// ---------------- K2: in-place wlast -> exclusive chunk carries -------------
__global__ void carry2(const float* __restrict__ Adiag, float* __restrict__ wl) {
    int gid = blockIdx.x * 256 + threadIdx.x;   // 16384 = B*H
    int b = gid >> 9, h = gid & (Hc - 1);
    float a = Adiag[h];
    float a64 = a;
#pragma unroll
    for (int i = 0; i < 6; i++) a64 *= a64;     // a^64
    float run = 0.f;
#pragma unroll 4
    for (int k = 0; k < NCc; k++) {
        size_t idx = ((size_t)b * NCc + k) * Hc + h;
        float tmp = wl[idx];
        wl[idx] = run;
        run = fmaf(a64, run, tmp);
    }
}

// ---------------- K3: full scan + fused y = h @ c ---------------------------
// NOTE (R3/R8 lesson): MFMA accumulators share the unified VGPR/AGPR file.
// Live set acc(32)+yacc(16)+xf(4)+misc lands ~150 regs total; min-waves=4
// caps at 128 and SPILLS (R8: FETCH 89MB/WRITE 112MB scratch, 116us).
// min-waves=3 caps at ~170 -> no spill (R5: clean FETCH at 21.5MB).
__global__ __launch_bounds__(256, 3) void pass2(
    const float* __restrict__ x, const short* __restrict__ bfrag,
    const short* __restrict__ cfrag, const float* __restrict__ Adiag,
    const float* __restrict__ carryC, float* __restrict__ out) {
    __shared__ char hbuf[64 * 256];        // [t][h-sub] bf16, swizzled, 16 KB
    __shared__ float aggw[2][WPB][HSUB];   // wave totals -> per-wave carries, dbuf

    const int tid = threadIdx.x;
    const int chunk = blockIdx.x, b = blockIdx.y;
    const int l = tid & 63, wid = tid >> 6;
    const int lr = l & 15, g = l >> 4;

    short8 xf[2];
    load_xfrag(x, b, chunk * Lc, wid, lr, g, xf);

    // hoist the 4 per-hsu chunk-carry loads out of the loop (they depend on
    // nothing computed here); selected below with compile-time-safe ternaries.
    float C0 = 0.f, C1 = 0.f, C2 = 0.f, C3 = 0.f;
    if (tid < HSUB) {
        const float* cb = carryC + (size_t)(b * NCc + chunk) * Hc + tid;
        C0 = cb[0]; C1 = cb[128]; C2 = cb[256]; C3 = cb[384];
    }

    float4v yacc[4];
#pragma unroll
    for (int j = 0; j < 4; j++) yacc[j] = (float4v)0.f;

#pragma unroll 1
    for (int hsu = 0; hsu < NSUB; hsu++) {
        const int buf = hsu & 1;
        float4v acc[8];   // lane-local xb -> in-wave inclusive scan values
        float areg[8];

        // ---- xb MFMA + in-wave scan (8 independent chains, free scheduling) ----
#pragma unroll
        for (int hj = 0; hj < 8; hj++) {
            const short8* bfp = (const short8*)bfrag + ((hsu * 8 + hj) * 2) * 64 + l;
            short8 b0 = bfp[0];
            short8 b1 = bfp[64];
            float4v t = (float4v)0.f;
            t = __builtin_amdgcn_mfma_f32_16x16x32_bf16(xf[0], b0, t, 0, 0, 0);
            t = __builtin_amdgcn_mfma_f32_16x16x32_bf16(xf[1], b1, t, 0, 0, 0);
            float a = Adiag[hsu * HSUB + hj * 16 + lr];
            areg[hj] = a;
            float a2 = a * a, a3 = a2 * a, a4 = a2 * a2, a8 = a4 * a4;
            // lane-local inclusive 4-step scan
            t[1] = fmaf(t[0], a, t[1]); t[2] = fmaf(t[1], a, t[2]); t[3] = fmaf(t[2], a, t[3]);
            // Hillis-Steele across the 4 lane-groups
            float s = t[3];
            float u = __shfl_up(s, 16u, 64); s = (g >= 1) ? fmaf(u, a4, s) : s;
            u = __shfl_up(s, 32u, 64);       s = (g >= 2) ? fmaf(u, a8, s) : s;
            float E = __shfl_up(s, 16u, 64); E = (g >= 1) ? E : 0.f;   // in-wave exclusive
#pragma unroll
            for (int r = 0; r < 4; r++) {
                float apr = (r == 0) ? a : (r == 1) ? a2 : (r == 2) ? a3 : a4;
                t[r] = fmaf(apr, E, t[r]);
            }
            acc[hj] = t;
            float S16 = __shfl(s, lr + 48, 64);
            if (l < 16) aggw[buf][wid][hj * 16 + l] = S16;
        }
        __syncthreads();   // wave totals visible

        // ---- chunk carry -> per-wave carries (in-place overwrite) ----
        if (tid < HSUB) {
            float a = Adiag[hsu * HSUB + tid];
            float t2 = a * a, t4 = t2 * t2, t8 = t4 * t4;
            float a16 = t8 * t8;
            float C = (hsu == 0) ? C0 : (hsu == 1) ? C1 : (hsu == 2) ? C2 : C3;
            float s0 = aggw[buf][0][tid], s1 = aggw[buf][1][tid], s2 = aggw[buf][2][tid];
            float P = C;
            aggw[buf][0][tid] = P; P = fmaf(a16, P, s0);
            aggw[buf][1][tid] = P; P = fmaf(a16, P, s1);
            aggw[buf][2][tid] = P; P = fmaf(a16, P, s2);
            aggw[buf][3][tid] = P;
        }
        __syncthreads();   // carries ready

        // ---- carry correction, h -> LDS (own-wave rows, no barrier) ----
#pragma unroll
        for (int hj = 0; hj < 8; hj++) {
            float P = aggw[buf][wid][hj * 16 + lr];
            float a = areg[hj];
            float a2 = a * a, a3 = a2 * a, a4 = a2 * a2, a8 = a4 * a4;
            float a4g = ((g & 1) ? a4 : 1.f) * ((g & 2) ? a8 : 1.f);
            float cc = a4g * P;
#pragma unroll
            for (int r = 0; r < 4; r++) {
                float apr = (r == 0) ? a : (r == 1) ? a2 : (r == 2) ? a3 : a4;
                float hv = fmaf(apr, cc, acc[hj][r]);
                *(short*)(hbuf + swz(wid * 16 + g * 4 + r, (hj * 16 + lr) * 2)) = f2bf(hv);
            }
        }

        // ---- y += h @ c (A-frags from own-wave hbuf rows) ----
#pragma unroll
        for (int ks = 0; ks < 4; ks++) {
            short8 af = *(const short8*)(hbuf + swz(wid * 16 + lr, ks * 64 + g * 16));
#pragma unroll
            for (int oj = 0; oj < 4; oj++) {
                short8 cf = *((const short8*)cfrag + ((hsu * 4 + ks) * 4 + oj) * 64 + l);
                yacc[oj] = __builtin_amdgcn_mfma_f32_16x16x32_bf16(af, cf, yacc[oj], 0, 0, 0);
            }
        }
    }

    // ---- write y tile (wave's 16 rows x 64 o) ----
    float* og = out + ((size_t)b * Sc + chunk * Lc) * Oc;
#pragma unroll
    for (int oj = 0; oj < 4; oj++)
#pragma unroll
        for (int r = 0; r < 4; r++) {
            int t = wid * 16 + g * 4 + r;
            og[t * Oc + oj * 16 + lr] = yacc[oj][r];
        }
}

// ---------------- host launch ----------------
extern "C" void kernel_launch(void* const* d_in, const int* in_sizes, int n_in,
                              void* d_out, int out_size, void* d_ws, size_t ws_size,
                              hipStream_t stream) {
    (void)in_sizes; (void)n_in; (void)out_size; (void)ws_size;
    const float* x     = (const float*)d_in[0];   // [B,S,I] f32
    const float* bw    = (const float*)d_in[1];   // [I,H]   f32
    const float* Adiag = (const float*)d_in[2];   // [H]     f32
    const float* cw    = (const float*)d_in[3];   // [H,O]   f32
    float* out = (float*)d_out;                   // [B,S*O] f32

    // workspace: ~4.2 MB
    float* wlast = (float*)d_ws;                              // [B][NC][H] f32, 4 MB
    short* bfrag = (short*)(wlast + (size_t)Bc * NCc * Hc);   // 64 KB
    short* cfrag = bfrag + 4096 * 8;                          // 64 KB

    prep_weights<<<32, 256, 0, stream>>>(bw, cw, bfrag, cfrag);
    pass1<<<dim3(NCc, Bc), 256, 0, stream>>>(x, bfrag, Adiag, wlast);
    carry2<<<64, 256, 0, stream>>>(Adiag, wlast);
    pass2<<<dim3(NCc, Bc), 256, 0, stream>>>(x, bfrag, cfrag, Adiag, wlast, out);
}